// Round 8
// baseline (31.550 us; speedup 1.0000x reference)
//
#include <hip/hip_runtime.h>

#define BATCHES  256
#define NVIEWS   20
#define CHANNELS 4096
#define KSEL     7
#define CHUNKS   (CHANNELS / 4)    // 1024 float4 per view row
#define QSPLIT   4                 // k1 blocks per batch
#define NT1      256
#define CPB      (CHUNKS / QSPLIT) // 256 chunks per k1 block (1 per thread)

// ---------------- kernel 1: streaming argmax + partial histograms ----------
// grid (QSPLIT, BATCHES), 256 threads. Running-best over the 20 strided
// loads: no register hold, ~40 VGPR, 4 blocks/CU -> full streaming overlap.
__global__ __launch_bounds__(NT1) void hist_kernel(
    const float* __restrict__ F0,      // [B, N, C]
    int* __restrict__ partial)         // [B][QSPLIT][NVIEWS]
{
    const int q = blockIdx.x;
    const int b = blockIdx.y;
    const int t = threadIdx.x;
    const int wave = t >> 6, lane = t & 63;

    __shared__ int wh[NT1 / 64][NVIEWS];
    if (lane < NVIEWS) wh[wave][lane] = 0;   // own-wave init precedes own-wave
                                             // atomics in program order

    const float4* Fb4 = (const float4*)(F0 + (size_t)b * NVIEWS * CHANNELS);
    const int c = q * CPB + t;

    float4 best = Fb4[c];                    // n = 0
    int bi0 = 0, bi1 = 0, bi2 = 0, bi3 = 0;
    #pragma unroll
    for (int n = 1; n < NVIEWS; ++n) {
        float4 v = Fb4[(size_t)n * CHUNKS + c];
        if (v.x > best.x) { best.x = v.x; bi0 = n; }
        if (v.y > best.y) { best.y = v.y; bi1 = n; }
        if (v.z > best.z) { best.z = v.z; bi2 = n; }
        if (v.w > best.w) { best.w = v.w; bi3 = n; }
    }
    atomicAdd(&wh[wave][bi0], 1);
    atomicAdd(&wh[wave][bi1], 1);
    atomicAdd(&wh[wave][bi2], 1);
    atomicAdd(&wh[wave][bi3], 1);
    __syncthreads();

    if (t < NVIEWS)
        partial[((size_t)b * QSPLIT + q) * NVIEWS + t] =
            wh[0][t] + wh[1][t] + wh[2][t] + wh[3][t];
}

// ---------------- kernel 2: selection (redundant per block) + gather -------
// grid (KSEL, BATCHES), 256 threads: block (j, b) copies row sidx[j] of
// batch b. F0 is L3-resident after k1, so reads are L3 hits; write-bound.
__global__ __launch_bounds__(256) void gather_kernel(
    const float* __restrict__ F0,      // [B, N, C]
    const float* __restrict__ V0,      // [B, N, 3]
    const int* __restrict__ partial,   // [B][QSPLIT][NVIEWS]
    float* __restrict__ out)           // [B*7*C] ++ [B*7*3]
{
    const int j = blockIdx.x;
    const int b = blockIdx.y;
    const int t = threadIdx.x;

    __shared__ int s_iv;

    if (t == 0) {
        // reassemble full-batch counts (identical integers to fused version)
        int counts[NVIEWS];
        const int* p = partial + (size_t)b * QSPLIT * NVIEWS;
        #pragma unroll
        for (int n = 0; n < NVIEWS; ++n)
            counts[n] = p[n] + p[NVIEWS + n] + p[2 * NVIEWS + n] + p[3 * NVIEWS + n];

        int u = 0;
        #pragma unroll
        for (int n = 0; n < NVIEWS; ++n) u += (counts[n] > 0) ? 1 : 0;

        int sidx[KSEL];
        if (u >= KSEL) {
            // top-7 by count, ties -> lower view id (== lax.top_k semantics)
            for (int jj = 0; jj < KSEL; ++jj) {
                int bestn = 0, bestc = counts[0];
                for (int n = 1; n < NVIEWS; ++n)
                    if (counts[n] > bestc) { bestc = counts[n]; bestn = n; }
                sidx[jj] = bestn;
                counts[bestn] = -1;
            }
        } else {
            // sorted unique ids, left-padded with the smallest
            int uniq[NVIEWS]; int m = 0;
            for (int n = 0; n < NVIEWS; ++n)
                if (counts[n] > 0) uniq[m++] = n;
            for (int jj = 0; jj < KSEL; ++jj) {
                int pp = jj - (KSEL - u);
                if (pp < 0) pp = 0;
                sidx[jj] = uniq[pp];
            }
        }
        s_iv = sidx[j];
    }
    __syncthreads();
    const int iv = s_iv;

    // copy the selected 16 KB row (4 float4 per thread, coalesced)
    const float4* src = (const float4*)(F0 + ((size_t)b * NVIEWS + iv) * CHANNELS);
    float4* dst = (float4*)out + ((size_t)b * KSEL + j) * CHUNKS;
    #pragma unroll
    for (int k = 0; k < 4; ++k)
        dst[t + k * 256] = src[t + k * 256];

    if (t < 3) {
        out[(size_t)BATCHES * KSEL * CHANNELS + ((size_t)b * KSEL + j) * 3 + t] =
            V0[((size_t)b * NVIEWS + iv) * 3 + t];
    }
}

extern "C" void kernel_launch(void* const* d_in, const int* in_sizes, int n_in,
                              void* d_out, int out_size, void* d_ws, size_t ws_size,
                              hipStream_t stream) {
    const float* F0 = (const float*)d_in[0];
    const float* V0 = (const float*)d_in[1];
    float* out = (float*)d_out;
    int* partial = (int*)d_ws;   // [256][4][20] int32 = 80 KB, fully rewritten
                                 // by k1 every call (no zero-init needed)

    dim3 g1(QSPLIT, BATCHES);
    hist_kernel<<<g1, NT1, 0, stream>>>(F0, partial);

    dim3 g2(KSEL, BATCHES);
    gather_kernel<<<g2, 256, 0, stream>>>(F0, V0, partial, out);
}

// Round 9
// 28.465 us; speedup vs baseline: 1.1084x; 1.1084x over previous
//
#include <hip/hip_runtime.h>

#define BATCHES  256
#define NVIEWS   20
#define CHANNELS 4096
#define KSEL     7
#define CHUNKS   (CHANNELS / 4)    // 1024 float4 per view row
#define QSPLIT   4                 // k1 blocks per batch
#define NT1      256
#define CPB      (CHUNKS / QSPLIT) // 256 chunks per k1 block (1 per thread)

// ---------------- kernel 1: max-MLP streaming argmax + partial histograms --
// grid (QSPLIT, BATCHES) = 1024 blocks, NT=256.
// __launch_bounds__(256,4): 4 waves/EU -> 4 blocks/CU, VGPR budget 128.
// Explicit v[20] hold (80 VGPR) guarantees all 20 loads in flight.
__global__ __launch_bounds__(NT1, 4) void hist_kernel(
    const float* __restrict__ F0,      // [B, N, C]
    int* __restrict__ partial)         // [B][QSPLIT][NVIEWS]
{
    const int q = blockIdx.x;
    const int b = blockIdx.y;
    const int t = threadIdx.x;
    const int wave = t >> 6, lane = t & 63;

    __shared__ int wh[NT1 / 64][NVIEWS];
    if (lane < NVIEWS) wh[wave][lane] = 0;   // own-wave init precedes own-wave
                                             // atomics in program order

    const float4* Fb4 = (const float4*)(F0 + (size_t)b * NVIEWS * CHANNELS);
    const int c = q * CPB + t;

    float4 v[NVIEWS];
    #pragma unroll
    for (int n = 0; n < NVIEWS; ++n)
        v[n] = Fb4[(size_t)n * CHUNKS + c];

    float4 best = v[0];
    int bi0 = 0, bi1 = 0, bi2 = 0, bi3 = 0;
    #pragma unroll
    for (int n = 1; n < NVIEWS; ++n) {
        if (v[n].x > best.x) { best.x = v[n].x; bi0 = n; }
        if (v[n].y > best.y) { best.y = v[n].y; bi1 = n; }
        if (v[n].z > best.z) { best.z = v[n].z; bi2 = n; }
        if (v[n].w > best.w) { best.w = v[n].w; bi3 = n; }
    }
    atomicAdd(&wh[wave][bi0], 1);
    atomicAdd(&wh[wave][bi1], 1);
    atomicAdd(&wh[wave][bi2], 1);
    atomicAdd(&wh[wave][bi3], 1);
    __syncthreads();

    if (t < NVIEWS)
        partial[((size_t)b * QSPLIT + q) * NVIEWS + t] =
            wh[0][t] + wh[1][t] + wh[2][t] + wh[3][t];
}

// ---------------- kernel 2: ONE block per batch: combine + select + gather -
// grid (BATCHES), NT=1024. Selection happens 256x total (not 1792x as in R8,
// whose per-block serial thread-0 selection latency x 7 blocks/CU was the
// ~10us regression). F0 rows are L3-resident after k1 -> write-bound.
__global__ __launch_bounds__(1024, 4) void gather_kernel(
    const float* __restrict__ F0,      // [B, N, C]
    const float* __restrict__ V0,      // [B, N, 3]
    const int* __restrict__ partial,   // [B][QSPLIT][NVIEWS]
    float* __restrict__ out)           // [B*7*C] ++ [B*7*3]
{
    const int b = blockIdx.x;
    const int t = threadIdx.x;

    __shared__ int s_counts[NVIEWS];
    __shared__ int s_sidx[KSEL];

    if (t < NVIEWS) {
        const int* p = partial + (size_t)b * QSPLIT * NVIEWS;
        s_counts[t] = p[t] + p[NVIEWS + t] + p[2 * NVIEWS + t] + p[3 * NVIEWS + t];
    }
    __syncthreads();

    if (t == 0) {
        int counts[NVIEWS];
        #pragma unroll
        for (int n = 0; n < NVIEWS; ++n) counts[n] = s_counts[n];

        int u = 0;
        #pragma unroll
        for (int n = 0; n < NVIEWS; ++n) u += (counts[n] > 0) ? 1 : 0;

        if (u >= KSEL) {
            // top-7 by count, ties -> lower view id (== lax.top_k semantics)
            for (int j = 0; j < KSEL; ++j) {
                int bestn = 0, bestc = counts[0];
                for (int n = 1; n < NVIEWS; ++n)
                    if (counts[n] > bestc) { bestc = counts[n]; bestn = n; }
                s_sidx[j] = bestn;
                counts[bestn] = -1;
            }
        } else {
            // sorted unique ids, left-padded with the smallest
            int uniq[NVIEWS]; int m = 0;
            for (int n = 0; n < NVIEWS; ++n)
                if (counts[n] > 0) uniq[m++] = n;
            for (int j = 0; j < KSEL; ++j) {
                int p = j - (KSEL - u);
                if (p < 0) p = 0;
                s_sidx[j] = uniq[p];
            }
        }
    }
    __syncthreads();

    // copy 7 rows (112 KB): thread t moves chunk t of each selected row
    const float4* Fb4 = (const float4*)(F0 + (size_t)b * NVIEWS * CHANNELS);
    float4* dst = (float4*)out + (size_t)b * KSEL * CHUNKS;
    #pragma unroll
    for (int j = 0; j < KSEL; ++j) {
        int iv = __builtin_amdgcn_readfirstlane(s_sidx[j]);
        dst[(size_t)j * CHUNKS + t] = Fb4[(size_t)iv * CHUNKS + t];
    }

    if (t < KSEL * 3) {
        int j = t / 3;
        out[(size_t)BATCHES * KSEL * CHANNELS + (size_t)b * KSEL * 3 + t] =
            V0[((size_t)b * NVIEWS + s_sidx[j]) * 3 + (t % 3)];
    }
}

extern "C" void kernel_launch(void* const* d_in, const int* in_sizes, int n_in,
                              void* d_out, int out_size, void* d_ws, size_t ws_size,
                              hipStream_t stream) {
    const float* F0 = (const float*)d_in[0];
    const float* V0 = (const float*)d_in[1];
    float* out = (float*)d_out;
    int* partial = (int*)d_ws;   // [256][4][20] int32 = 80 KB, fully rewritten
                                 // by k1 every call (no zero-init needed)

    dim3 g1(QSPLIT, BATCHES);
    hist_kernel<<<g1, NT1, 0, stream>>>(F0, partial);

    gather_kernel<<<BATCHES, 1024, 0, stream>>>(F0, V0, partial, out);
}

// Round 11
// 22.643 us; speedup vs baseline: 1.3934x; 1.2571x over previous
//
#include <hip/hip_runtime.h>

#define BATCHES  256
#define NVIEWS   20
#define CHANNELS 4096
#define KSEL     7
#define NT       1024        // threads/block; CHANNELS/4 == 1024 float4 chunks
#define NWAVES   (NT / 64)

// native 16B vector type: __builtin_nontemporal_store rejects HIP_vector_type
typedef float f32x4 __attribute__((ext_vector_type(4)));

// grid = 256 blocks = 1/CU regardless, so the 80-VGPR v[20] hold is free:
// __launch_bounds__(1024, 4) -> 128-VGPR budget, no spill (R6 lesson: without
// the waves arg the compiler capped at 64 and spilled everything).
__global__ __launch_bounds__(NT, 4) void view_select_kernel(
    const float* __restrict__ F0,     // [B, N, C]
    const float* __restrict__ V0,     // [B, N, 3]
    float* __restrict__ out)          // [B*7*C] ++ [B*7*3]
{
    const int b    = blockIdx.x;
    const int t    = threadIdx.x;
    const int wave = t >> 6;
    const int lane = t & 63;

    __shared__ int wh[NWAVES][NVIEWS];   // per-wave histograms
    __shared__ int s_counts[NVIEWS];
    __shared__ int s_sidx[KSEL];

    if (lane < NVIEWS) wh[wave][lane] = 0;   // own-wave init precedes own-wave
                                             // atomics in program order

    // ---- phase 1: hold all 20 views in registers, argmax, histogram ----
    const f32x4* Fb4 = (const f32x4*)(F0 + (size_t)b * NVIEWS * CHANNELS);

    f32x4 v[NVIEWS];
    #pragma unroll
    for (int n = 0; n < NVIEWS; ++n)
        v[n] = Fb4[(size_t)n * (CHANNELS / 4) + t];

    f32x4 best = v[0];
    int bi0 = 0, bi1 = 0, bi2 = 0, bi3 = 0;
    #pragma unroll
    for (int n = 1; n < NVIEWS; ++n) {
        if (v[n].x > best.x) { best.x = v[n].x; bi0 = n; }
        if (v[n].y > best.y) { best.y = v[n].y; bi1 = n; }
        if (v[n].z > best.z) { best.z = v[n].z; bi2 = n; }
        if (v[n].w > best.w) { best.w = v[n].w; bi3 = n; }
    }
    atomicAdd(&wh[wave][bi0], 1);
    atomicAdd(&wh[wave][bi1], 1);
    atomicAdd(&wh[wave][bi2], 1);
    atomicAdd(&wh[wave][bi3], 1);
    __syncthreads();

    // combine per-wave histograms (lanes 0..19 of the block)
    if (t < NVIEWS) {
        int s = 0;
        #pragma unroll
        for (int w = 0; w < NWAVES; ++w) s += wh[w][t];
        s_counts[t] = s;
    }
    __syncthreads();

    // ---- phase 2: wave-parallel selection (replaces serial thread-0) ----
    // topk branch: rank[n] = #{m: c[m]>c[n] or (c[m]==c[n] and m<n)};
    //   selected iff rank<7; s_sidx[rank]=n  == lax.top_k ties->lower id.
    // pad branch (u<7): unique view with ascending position p goes to slot
    //   p+(7-u); p==0 additionally fills slots 0..6-u (left replication).
    if (t < NVIEWS) {
        const int myc = s_counts[t];
        int u = 0, rank = 0, pos = 0;
        #pragma unroll
        for (int m = 0; m < NVIEWS; ++m) {
            const int cm = s_counts[m];
            u    += (cm > 0) ? 1 : 0;
            rank += ((cm > myc) || (cm == myc && m < t)) ? 1 : 0;
            pos  += ((m < t) && (cm > 0)) ? 1 : 0;
        }
        if (u >= KSEL) {
            if (rank < KSEL) s_sidx[rank] = t;
        } else if (myc > 0) {
            const int base = KSEL - u;
            s_sidx[pos + base] = t;
            if (pos == 0)
                for (int j = 0; j < base; ++j) s_sidx[j] = t;
        }
    }
    __syncthreads();

    // ---- phase 3: WRITE-ONLY gather from held registers (NT stores) ----
    // out is never re-read on device: non-temporal stores keep the 29.4 MB
    // output from displacing F0 in L2/L3 (R6: FETCH 42<84 MB -> L3 carries
    // F0 across replays; preserve that).
    if (t < KSEL * 3) {
        const int j = t / 3;
        __builtin_nontemporal_store(
            V0[((size_t)b * NVIEWS + s_sidx[j]) * 3 + (t % 3)],
            &out[(size_t)BATCHES * KSEL * CHANNELS + (size_t)b * KSEL * 3 + t]);
    }

    f32x4* out4 = (f32x4*)out;
    const size_t ob = (size_t)b * KSEL * (CHANNELS / 4);
    #pragma unroll
    for (int j = 0; j < KSEL; ++j) {
        const int iv = __builtin_amdgcn_readfirstlane(s_sidx[j]);
        #pragma unroll
        for (int n = 0; n < NVIEWS; ++n) {
            if (iv == n)   // wave-uniform scalar branch: 19 bodies skipped
                __builtin_nontemporal_store(
                    v[n], &out4[ob + (size_t)j * (CHANNELS / 4) + t]);
        }
    }
}

extern "C" void kernel_launch(void* const* d_in, const int* in_sizes, int n_in,
                              void* d_out, int out_size, void* d_ws, size_t ws_size,
                              hipStream_t stream) {
    const float* F0 = (const float*)d_in[0];
    const float* V0 = (const float*)d_in[1];
    float* out = (float*)d_out;

    view_select_kernel<<<BATCHES, NT, 0, stream>>>(F0, V0, out);
}

// Round 12
// 22.556 us; speedup vs baseline: 1.3987x; 1.0038x over previous
//
#include <hip/hip_runtime.h>

#define BATCHES  256
#define NVIEWS   20
#define CHANNELS 4096
#define KSEL     7
#define NT       1024        // threads/block; CHANNELS/4 == 1024 float4 chunks
#define NWAVES   (NT / 64)

// native 16B vector type: __builtin_nontemporal_store rejects HIP_vector_type
typedef float f32x4 __attribute__((ext_vector_type(4)));

// grid = 256 blocks = 1/CU regardless, so the 80-VGPR v[20] hold is free:
// __launch_bounds__(1024, 4) -> 128-VGPR budget, no spill (R6 lesson: without
// the waves arg the compiler capped at 64 and spilled everything).
__global__ __launch_bounds__(NT, 4) void view_select_kernel(
    const float* __restrict__ F0,     // [B, N, C]
    const float* __restrict__ V0,     // [B, N, 3]
    float* __restrict__ out)          // [B*7*C] ++ [B*7*3]
{
    const int b    = blockIdx.x;
    const int t    = threadIdx.x;
    const int wave = t >> 6;
    const int lane = t & 63;

    __shared__ int wh[NWAVES][NVIEWS];   // per-wave histograms
    __shared__ int s_sidx[KSEL];

    if (lane < NVIEWS) wh[wave][lane] = 0;   // own-wave init precedes own-wave
                                             // atomics in program order

    // ---- phase 1: hold all 20 views in registers, argmax, histogram ----
    const f32x4* Fb4 = (const f32x4*)(F0 + (size_t)b * NVIEWS * CHANNELS);

    f32x4 v[NVIEWS];
    #pragma unroll
    for (int n = 0; n < NVIEWS; ++n)
        v[n] = Fb4[(size_t)n * (CHANNELS / 4) + t];

    f32x4 best = v[0];
    int bi0 = 0, bi1 = 0, bi2 = 0, bi3 = 0;
    #pragma unroll
    for (int n = 1; n < NVIEWS; ++n) {
        if (v[n].x > best.x) { best.x = v[n].x; bi0 = n; }
        if (v[n].y > best.y) { best.y = v[n].y; bi1 = n; }
        if (v[n].z > best.z) { best.z = v[n].z; bi2 = n; }
        if (v[n].w > best.w) { best.w = v[n].w; bi3 = n; }
    }
    atomicAdd(&wh[wave][bi0], 1);
    atomicAdd(&wh[wave][bi1], 1);
    atomicAdd(&wh[wave][bi2], 1);
    atomicAdd(&wh[wave][bi3], 1);
    __syncthreads();                         // barrier 1: all histograms done

    // ---- phase 2: fused combine+select, entirely inside wave 0 ----
    // Lane n (n<20) sums bin n across the 16 per-wave histograms; the 20
    // counts are then exchanged with __shfl (wave-lockstep, no barrier, no
    // LDS round-trip — saves barrier #2 of the R11 version).
    // topk branch: rank[n] = #{m: c[m]>c[n] or (c[m]==c[n] and m<n)};
    //   selected iff rank<7; s_sidx[rank]=n  == lax.top_k ties->lower id.
    // pad branch (u<7): unique view at ascending position p -> slot p+(7-u);
    //   p==0 also fills slots 0..6-u (left replication).
    if (wave == 0) {
        int myc = 0;
        if (lane < NVIEWS) {
            #pragma unroll
            for (int w = 0; w < NWAVES; ++w) myc += wh[w][lane];
        }
        int u = 0, rank = 0, pos = 0;
        #pragma unroll
        for (int m = 0; m < NVIEWS; ++m) {
            const int cm = __shfl(myc, m, 64);   // lanes >=20 compute garbage
            u    += (cm > 0) ? 1 : 0;            // but never write below
            rank += ((cm > myc) || (cm == myc && m < lane)) ? 1 : 0;
            pos  += ((m < lane) && (cm > 0)) ? 1 : 0;
        }
        if (lane < NVIEWS) {
            if (u >= KSEL) {
                if (rank < KSEL) s_sidx[rank] = lane;
            } else if (myc > 0) {
                const int base = KSEL - u;
                s_sidx[pos + base] = lane;
                if (pos == 0)
                    for (int j = 0; j < base; ++j) s_sidx[j] = lane;
            }
        }
    }
    __syncthreads();                         // barrier 2: s_sidx visible

    // ---- phase 3: WRITE-ONLY gather from held registers (NT stores) ----
    // out is never re-read on device: non-temporal stores keep the 29.4 MB
    // output from displacing F0 in L2/L3.
    if (t < KSEL * 3) {
        const int j = t / 3;
        __builtin_nontemporal_store(
            V0[((size_t)b * NVIEWS + s_sidx[j]) * 3 + (t % 3)],
            &out[(size_t)BATCHES * KSEL * CHANNELS + (size_t)b * KSEL * 3 + t]);
    }

    f32x4* out4 = (f32x4*)out;
    const size_t ob = (size_t)b * KSEL * (CHANNELS / 4);
    #pragma unroll
    for (int j = 0; j < KSEL; ++j) {
        const int iv = __builtin_amdgcn_readfirstlane(s_sidx[j]);
        #pragma unroll
        for (int n = 0; n < NVIEWS; ++n) {
            if (iv == n)   // wave-uniform scalar branch: 19 bodies skipped
                __builtin_nontemporal_store(
                    v[n], &out4[ob + (size_t)j * (CHANNELS / 4) + t]);
        }
    }
}

extern "C" void kernel_launch(void* const* d_in, const int* in_sizes, int n_in,
                              void* d_out, int out_size, void* d_ws, size_t ws_size,
                              hipStream_t stream) {
    const float* F0 = (const float*)d_in[0];
    const float* V0 = (const float*)d_in[1];
    float* out = (float*)d_out;

    view_select_kernel<<<BATCHES, NT, 0, stream>>>(F0, V0, out);
}